// Round 1
// baseline (902.418 us; speedup 1.0000x reference)
//
#include <hip/hip_runtime.h>
#include <cstdint>
#include <cstddef>

#define SS 2048
#define BB 4
#define DD 512
#define HH 8
#define HDD 64
#define SBB (SS*BB)

// XOR-swizzle on the 0..63 "column" index of a [k][64] LDS tile.
// XORs bits 2-4 with bits 2-4 of k: float4 blocks stay aligned/contiguous.
__device__ __forceinline__ int sw8(int k, int s) { return s ^ (((k >> 2) & 7) << 2); }

// ---------------- K1: QKV projection ----------------
// C[r][j] = sum_i X[r][i] * W[j][i] + bias[j], scattered into Q/K/V [B][H][S][HD]
// Q gets *0.125 (1/sqrt(HD)), V gets *gate[b].
__global__ __launch_bounds__(256) void qkv_kernel(
    const float* __restrict__ X, const float* __restrict__ W,
    const float* __restrict__ bias, const float* __restrict__ gate,
    float* __restrict__ Qo, float* __restrict__ Ko, float* __restrict__ Vo)
{
    __shared__ float As[32][64];
    __shared__ float Bs[32][64];
    const int tid = threadIdx.x;
    const int tx = tid & 15, ty = tid >> 4;
    const int j0 = blockIdx.x * 64;
    const int r0 = blockIdx.y * 64;
    float acc[4][4] = {};
    for (int k0 = 0; k0 < DD; k0 += 32) {
#pragma unroll
        for (int p = 0; p < 2; ++p) {
            const int idx = tid + p * 256;
            const int row = idx >> 3;        // 0..63
            const int kk = (idx & 7) << 2;   // 0..28
            const float4 av = *(const float4*)(X + (size_t)(r0 + row) * DD + k0 + kk);
            const float4 bv = *(const float4*)(W + (size_t)(j0 + row) * DD + k0 + kk);
            As[kk + 0][sw8(kk + 0, row)] = av.x;
            As[kk + 1][sw8(kk + 1, row)] = av.y;
            As[kk + 2][sw8(kk + 2, row)] = av.z;
            As[kk + 3][sw8(kk + 3, row)] = av.w;
            Bs[kk + 0][sw8(kk + 0, row)] = bv.x;
            Bs[kk + 1][sw8(kk + 1, row)] = bv.y;
            Bs[kk + 2][sw8(kk + 2, row)] = bv.z;
            Bs[kk + 3][sw8(kk + 3, row)] = bv.w;
        }
        __syncthreads();
#pragma unroll
        for (int k = 0; k < 32; ++k) {
            const float4 a = *(const float4*)&As[k][sw8(k, ty << 2)];
            const float4 b = *(const float4*)&Bs[k][sw8(k, tx << 2)];
            const float ar[4] = {a.x, a.y, a.z, a.w};
            const float br[4] = {b.x, b.y, b.z, b.w};
#pragma unroll
            for (int i = 0; i < 4; ++i)
#pragma unroll
                for (int j = 0; j < 4; ++j)
                    acc[i][j] = fmaf(ar[i], br[j], acc[i][j]);
        }
        __syncthreads();
    }
    const int sector = j0 >> 9;       // 0=q, 1=k, 2=v
    const int h = (j0 >> 6) & 7;
    const float4 b4 = *(const float4*)(bias + j0 + (tx << 2));
#pragma unroll
    for (int i = 0; i < 4; ++i) {
        const int r = r0 + (ty << 2) + i;
        const int s = r >> 2;         // r = s*B + b
        const int bb = r & 3;
        float4 o;
        o.x = acc[i][0] + b4.x; o.y = acc[i][1] + b4.y;
        o.z = acc[i][2] + b4.z; o.w = acc[i][3] + b4.w;
        const size_t dst = (((size_t)bb * HH + h) * SS + s) * HDD + (tx << 2);
        if (sector == 0) {
            o.x *= 0.125f; o.y *= 0.125f; o.z *= 0.125f; o.w *= 0.125f;
            *(float4*)(Qo + dst) = o;
        } else if (sector == 1) {
            *(float4*)(Ko + dst) = o;
        } else {
            const float g = gate[bb];
            o.x *= g; o.y *= g; o.z *= g; o.w *= g;
            *(float4*)(Vo + dst) = o;
        }
    }
}

// ---------------- K2: flash attention with additive head mask ----------------
// One block per (b, h, 64-row s-tile). bid laid out so the 4 batch variants of a
// given (h, s-tile) land on the same XCD (stride 8) for L2 mask reuse.
__global__ __launch_bounds__(256) void attn_kernel(
    const float* __restrict__ Q, const float* __restrict__ K, const float* __restrict__ V,
    const float* __restrict__ M, float* __restrict__ AO)
{
    __shared__ float Qt[64][64];   // [d][s], swizzled
    __shared__ float Kt[64][64];   // [d][t], swizzled
    __shared__ float Vs[64][64];   // [t][d], natural
    __shared__ float Pt[64][64];   // [t][s], swizzled
    const int tid = threadIdx.x;
    const int tx = tid & 15, ty = tid >> 4;
    const int bid = blockIdx.x;
    // hs = (h, s-tile) index; b varies with stride 8 in bid (same XCD phase)
    const int hs = ((bid >> 5) << 3) + (bid & 7);
    const int b = (bid >> 3) & 3;
    const int h = hs & 7;
    const int s0 = (hs >> 3) << 6;
    const float* Qp = Q + ((size_t)b * HH + h) * SS * HDD;
    const float* Kp = K + ((size_t)b * HH + h) * SS * HDD;
    const float* Vp = V + ((size_t)b * HH + h) * SS * HDD;
    const float* Mp = M + (size_t)h * SS * SS;

#pragma unroll
    for (int p = 0; p < 4; ++p) {
        const int idx = tid + p * 256;
        const int row = idx >> 4;        // 0..63
        const int dd = (idx & 15) << 2;  // 0..60
        const float4 qv = *(const float4*)(Qp + (size_t)(s0 + row) * HDD + dd);
        Qt[dd + 0][sw8(dd + 0, row)] = qv.x;
        Qt[dd + 1][sw8(dd + 1, row)] = qv.y;
        Qt[dd + 2][sw8(dd + 2, row)] = qv.z;
        Qt[dd + 3][sw8(dd + 3, row)] = qv.w;
    }
    float m[4], l[4], O[4][4] = {};
#pragma unroll
    for (int i = 0; i < 4; ++i) { m[i] = -1e30f; l[i] = 0.f; }

    for (int t0 = 0; t0 < SS; t0 += 64) {
        __syncthreads();  // previous iter's Pt/Vs reads done before overwrite
#pragma unroll
        for (int p = 0; p < 4; ++p) {
            const int idx = tid + p * 256;
            const int row = idx >> 4;
            const int dd = (idx & 15) << 2;
            const float4 kv = *(const float4*)(Kp + (size_t)(t0 + row) * HDD + dd);
            Kt[dd + 0][sw8(dd + 0, row)] = kv.x;
            Kt[dd + 1][sw8(dd + 1, row)] = kv.y;
            Kt[dd + 2][sw8(dd + 2, row)] = kv.z;
            Kt[dd + 3][sw8(dd + 3, row)] = kv.w;
            const float4 vv = *(const float4*)(Vp + (size_t)(t0 + row) * HDD + dd);
            *(float4*)&Vs[row][dd] = vv;
        }
        __syncthreads();
        float sc[4][4] = {};
#pragma unroll
        for (int k = 0; k < 64; ++k) {
            const float4 a = *(const float4*)&Qt[k][sw8(k, ty << 2)];
            const float4 bq = *(const float4*)&Kt[k][sw8(k, tx << 2)];
            const float ar[4] = {a.x, a.y, a.z, a.w};
            const float br[4] = {bq.x, bq.y, bq.z, bq.w};
#pragma unroll
            for (int i = 0; i < 4; ++i)
#pragma unroll
                for (int j = 0; j < 4; ++j)
                    sc[i][j] = fmaf(ar[i], br[j], sc[i][j]);
        }
        float pv[4][4];
#pragma unroll
        for (int i = 0; i < 4; ++i) {
            const int s = s0 + (ty << 2) + i;
            const float4 mv = *(const float4*)(Mp + (size_t)s * SS + t0 + (tx << 2));
            sc[i][0] += mv.x; sc[i][1] += mv.y; sc[i][2] += mv.z; sc[i][3] += mv.w;
            // row max over this tile (16 lanes of the row group + 4 local)
            float tm = fmaxf(fmaxf(sc[i][0], sc[i][1]), fmaxf(sc[i][2], sc[i][3]));
            tm = fmaxf(tm, __shfl_xor(tm, 1));
            tm = fmaxf(tm, __shfl_xor(tm, 2));
            tm = fmaxf(tm, __shfl_xor(tm, 4));
            tm = fmaxf(tm, __shfl_xor(tm, 8));
            const float mn = fmaxf(m[i], tm);
            const float alpha = __expf(m[i] - mn);
            float ps = 0.f;
#pragma unroll
            for (int j = 0; j < 4; ++j) { pv[i][j] = __expf(sc[i][j] - mn); ps += pv[i][j]; }
            ps += __shfl_xor(ps, 1);
            ps += __shfl_xor(ps, 2);
            ps += __shfl_xor(ps, 4);
            ps += __shfl_xor(ps, 8);
            l[i] = l[i] * alpha + ps;
            m[i] = mn;
#pragma unroll
            for (int j = 0; j < 4; ++j) O[i][j] *= alpha;
        }
        // stage P transposed [t][s] (float4 along s)
#pragma unroll
        for (int j = 0; j < 4; ++j) {
            const int t = (tx << 2) + j;
            float4 col;
            col.x = pv[0][j]; col.y = pv[1][j]; col.z = pv[2][j]; col.w = pv[3][j];
            *(float4*)&Pt[t][sw8(t, ty << 2)] = col;
        }
        __syncthreads();
#pragma unroll
        for (int k = 0; k < 64; ++k) {
            const float4 a = *(const float4*)&Pt[k][sw8(k, ty << 2)];
            const float4 vv = *(const float4*)&Vs[k][tx << 2];
            const float ar[4] = {a.x, a.y, a.z, a.w};
            const float vr[4] = {vv.x, vv.y, vv.z, vv.w};
#pragma unroll
            for (int i = 0; i < 4; ++i)
#pragma unroll
                for (int j = 0; j < 4; ++j)
                    O[i][j] = fmaf(ar[i], vr[j], O[i][j]);
        }
    }
#pragma unroll
    for (int i = 0; i < 4; ++i) {
        const int s = s0 + (ty << 2) + i;
        const float inv = 1.0f / l[i];
        float4 o;
        o.x = O[i][0] * inv; o.y = O[i][1] * inv; o.z = O[i][2] * inv; o.w = O[i][3] * inv;
        *(float4*)(AO + ((size_t)s * BB + b) * DD + h * HDD + (tx << 2)) = o;
    }
}

// ---------------- K3: output projection ----------------
__global__ __launch_bounds__(256) void oproj_kernel(
    const float* __restrict__ A, const float* __restrict__ W,
    const float* __restrict__ bias, float* __restrict__ Out)
{
    __shared__ float As[32][64];
    __shared__ float Bs[32][64];
    const int tid = threadIdx.x;
    const int tx = tid & 15, ty = tid >> 4;
    const int j0 = blockIdx.x * 64;
    const int r0 = blockIdx.y * 64;
    float acc[4][4] = {};
    for (int k0 = 0; k0 < DD; k0 += 32) {
#pragma unroll
        for (int p = 0; p < 2; ++p) {
            const int idx = tid + p * 256;
            const int row = idx >> 3;
            const int kk = (idx & 7) << 2;
            const float4 av = *(const float4*)(A + (size_t)(r0 + row) * DD + k0 + kk);
            const float4 bv = *(const float4*)(W + (size_t)(j0 + row) * DD + k0 + kk);
            As[kk + 0][sw8(kk + 0, row)] = av.x;
            As[kk + 1][sw8(kk + 1, row)] = av.y;
            As[kk + 2][sw8(kk + 2, row)] = av.z;
            As[kk + 3][sw8(kk + 3, row)] = av.w;
            Bs[kk + 0][sw8(kk + 0, row)] = bv.x;
            Bs[kk + 1][sw8(kk + 1, row)] = bv.y;
            Bs[kk + 2][sw8(kk + 2, row)] = bv.z;
            Bs[kk + 3][sw8(kk + 3, row)] = bv.w;
        }
        __syncthreads();
#pragma unroll
        for (int k = 0; k < 32; ++k) {
            const float4 a = *(const float4*)&As[k][sw8(k, ty << 2)];
            const float4 b = *(const float4*)&Bs[k][sw8(k, tx << 2)];
            const float ar[4] = {a.x, a.y, a.z, a.w};
            const float br[4] = {b.x, b.y, b.z, b.w};
#pragma unroll
            for (int i = 0; i < 4; ++i)
#pragma unroll
                for (int j = 0; j < 4; ++j)
                    acc[i][j] = fmaf(ar[i], br[j], acc[i][j]);
        }
        __syncthreads();
    }
    const float4 b4 = *(const float4*)(bias + j0 + (tx << 2));
#pragma unroll
    for (int i = 0; i < 4; ++i) {
        const int r = r0 + (ty << 2) + i;
        float4 o;
        o.x = acc[i][0] + b4.x; o.y = acc[i][1] + b4.y;
        o.z = acc[i][2] + b4.z; o.w = acc[i][3] + b4.w;
        *(float4*)(Out + (size_t)r * DD + j0 + (tx << 2)) = o;
    }
}

extern "C" void kernel_launch(void* const* d_in, const int* in_sizes, int n_in,
                              void* d_out, int out_size, void* d_ws, size_t ws_size,
                              hipStream_t stream)
{
    (void)in_sizes; (void)n_in; (void)out_size; (void)ws_size;
    const float* X    = (const float*)d_in[0];  // (S,B,D)
    const float* Mask = (const float*)d_in[1];  // (H,S,S)
    const float* gate = (const float*)d_in[2];  // (1,B,1)
    const float* Wi   = (const float*)d_in[3];  // (3D,D)
    const float* bi   = (const float*)d_in[4];  // (3D)
    const float* Wo   = (const float*)d_in[5];  // (D,D)
    const float* bo   = (const float*)d_in[6];  // (D)
    float* ws = (float*)d_ws;
    const size_t plane = (size_t)BB * HH * SS * HDD;  // 4M floats
    float* Q  = ws;
    float* K  = ws + plane;
    float* V  = ws + 2 * plane;
    float* AO = ws + 3 * plane;

    qkv_kernel<<<dim3(24, 128), 256, 0, stream>>>(X, Wi, bi, gate, Q, K, V);
    attn_kernel<<<dim3(1024), 256, 0, stream>>>(Q, K, V, Mask, AO);
    oproj_kernel<<<dim3(8, 128), 256, 0, stream>>>(AO, Wo, bo, (float*)d_out);
}

// Round 2
// 231.382 us; speedup vs baseline: 3.9001x; 3.9001x over previous
//
#include <hip/hip_runtime.h>
#include <cstdint>
#include <cstddef>

typedef _Float16 half8 __attribute__((ext_vector_type(8)));
typedef _Float16 half4 __attribute__((ext_vector_type(4)));
typedef float f32x4 __attribute__((ext_vector_type(4)));

#define MFMA16(A,B,C) __builtin_amdgcn_mfma_f32_16x16x32_f16(A,B,C,0,0,0)

// convert 8 consecutive f32 -> half8
__device__ __forceinline__ half8 cvt8(const float* p) {
    f32x4 v0 = *(const f32x4*)p;
    f32x4 v1 = *(const f32x4*)(p + 4);
    half8 r;
    r[0]=(_Float16)v0[0]; r[1]=(_Float16)v0[1]; r[2]=(_Float16)v0[2]; r[3]=(_Float16)v0[3];
    r[4]=(_Float16)v1[0]; r[5]=(_Float16)v1[1]; r[6]=(_Float16)v1[2]; r[7]=(_Float16)v1[3];
    return r;
}

// ---------------- K1: QKV projection (f16 MFMA) ----------------
// C[r][col] = sum_k X[r][k]*W[col][k] + bias; scatter to Q(*0.125)/K [b][h][s][64]
// and V^T (*gate[b]) [b][h][d][s], all f16.
__global__ __launch_bounds__(256) void qkv_mfma(
    const float* __restrict__ X, const float* __restrict__ W,
    const float* __restrict__ bias, const float* __restrict__ gate,
    _Float16* __restrict__ Qo, _Float16* __restrict__ Ko, _Float16* __restrict__ Vt)
{
    __shared__ _Float16 As[128][72];
    __shared__ _Float16 Bs[64][72];
    const int tid = threadIdx.x;
    const int lane = tid & 63, wv = tid >> 6;
    const int l15 = lane & 15, g = lane >> 4;
    const int wr = wv >> 1, wc = wv & 1;
    const int j0 = blockIdx.x * 64, r0 = blockIdx.y * 128;
    f32x4 acc[4][2] = {};
    const int arow = tid >> 1, ahf = tid & 1;
    const int brow = tid >> 2, bc = tid & 3;
    for (int k0 = 0; k0 < 512; k0 += 64) {
        const float* srca = X + (size_t)(r0 + arow) * 512 + k0 + ahf * 32;
#pragma unroll
        for (int c = 0; c < 4; ++c)
            *(half8*)&As[arow][ahf * 32 + c * 8] = cvt8(srca + c * 8);
        const float* srcb = W + (size_t)(j0 + brow) * 512 + k0 + bc * 16;
#pragma unroll
        for (int c = 0; c < 2; ++c)
            *(half8*)&Bs[brow][bc * 16 + c * 8] = cvt8(srcb + c * 8);
        __syncthreads();
#pragma unroll
        for (int kt = 0; kt < 2; ++kt) {
            half8 bf0 = *(half8*)&Bs[32 * wc + l15][kt * 32 + g * 8];
            half8 bf1 = *(half8*)&Bs[32 * wc + 16 + l15][kt * 32 + g * 8];
#pragma unroll
            for (int ri = 0; ri < 4; ++ri) {
                half8 af = *(half8*)&As[64 * wr + 16 * ri + l15][kt * 32 + g * 8];
                acc[ri][0] = MFMA16(af, bf0, acc[ri][0]);
                acc[ri][1] = MFMA16(af, bf1, acc[ri][1]);
            }
        }
        __syncthreads();
    }
#pragma unroll
    for (int ri = 0; ri < 4; ++ri) {
#pragma unroll
        for (int cj = 0; cj < 2; ++cj) {
            const int col = j0 + 32 * wc + 16 * cj + l15;
            const int sec = col >> 9, hh = (col >> 6) & 7, d = col & 63;
            const float bv = bias[col];
#pragma unroll
            for (int r = 0; r < 4; ++r) {
                const int row = r0 + 64 * wr + 16 * ri + 4 * g + r;
                const int b = row & 3, s = row >> 2;
                const float v = acc[ri][cj][r];
                if (sec == 0)
                    Qo[((size_t)(b * 8 + hh) * 2048 + s) * 64 + d] = (_Float16)((v + bv) * 0.125f);
                else if (sec == 1)
                    Ko[((size_t)(b * 8 + hh) * 2048 + s) * 64 + d] = (_Float16)(v + bv);
                else
                    Vt[((size_t)(b * 8 + hh) * 64 + d) * 2048 + s] = (_Float16)(v * gate[b] + bv);
            }
        }
    }
}

// ---------------- K2: flash attention, f16 MFMA, transposed scores ----------------
// Per block: 2 waves, wave w = batch bg*2+w, 64 q-rows. St[kv][q] = K·Q^T (+mask as
// C-init), softmax over kv (rows of St -> per-lane + shfl over g), O^T = V^T·P^T.
__global__ __launch_bounds__(128) void attn_mfma(
    const _Float16* __restrict__ Q, const _Float16* __restrict__ K,
    const _Float16* __restrict__ V, const float* __restrict__ M,
    _Float16* __restrict__ AO)
{
    __shared__ _Float16 Kl[2][64][72];
    __shared__ _Float16 Vl[2][64][72];
    const int tid = threadIdx.x;
    const int lane = tid & 63, w = tid >> 6;
    const int l15 = lane & 15, g = lane >> 4;
    const int bid = blockIdx.x;
    const int h = bid & 7, st = (bid >> 3) & 31, bg = bid >> 8;
    const int b = bg * 2 + w;
    const int s0 = st * 64;
    const size_t bh = (size_t)b * 8 + h;
    const _Float16* Qp = Q + bh * 2048 * 64;
    const _Float16* Kp = K + bh * 2048 * 64;
    const _Float16* Vp = V + bh * 64 * 2048;
    const float* Mp = M + (size_t)h * 2048 * 2048;

    // stage this wave's Q tile into Kl[w], grab fragments to registers
#pragma unroll
    for (int i = 0; i < 8; ++i) {
        const int c = i * 64 + lane;
        const int row = c >> 3, cc = c & 7;
        *(half8*)&Kl[w][row][cc * 8] = *(const half8*)(Qp + (size_t)(s0 + row) * 64 + cc * 8);
    }
    __syncthreads();
    half8 qf[4][2];
#pragma unroll
    for (int qj = 0; qj < 4; ++qj)
#pragma unroll
        for (int kt = 0; kt < 2; ++kt)
            qf[qj][kt] = *(half8*)&Kl[w][16 * qj + l15][kt * 32 + g * 8];

    f32x4 O[4][4] = {};
    float ms[4], ls[4];
#pragma unroll
    for (int qj = 0; qj < 4; ++qj) { ms[qj] = -1e30f; ls[qj] = 0.f; }

    for (int t0 = 0; t0 < 2048; t0 += 64) {
        __syncthreads();
        // stage K tile [kv][d] and V^T tile [d][kv] for this wave's batch
#pragma unroll
        for (int i = 0; i < 8; ++i) {
            const int row = i * 8 + (lane >> 3), cc = lane & 7;
            *(half8*)&Kl[w][row][cc * 8] = *(const half8*)(Kp + (size_t)(t0 + row) * 64 + cc * 8);
            *(half8*)&Vl[w][row][cc * 8] = *(const half8*)(Vp + (size_t)row * 2048 + t0 + cc * 8);
        }
        __syncthreads();
        // St[kv][q] initialized with mask[q][kv] (C-operand of MFMA)
        f32x4 St[4][4];
#pragma unroll
        for (int m = 0; m < 4; ++m)
#pragma unroll
            for (int qj = 0; qj < 4; ++qj)
                St[m][qj] = *(const f32x4*)(Mp + (size_t)(s0 + 16 * qj + l15) * 2048 + t0 + 16 * m + 4 * g);
        // QK^T (Q pre-scaled by 1/8)
#pragma unroll
        for (int kt = 0; kt < 2; ++kt)
#pragma unroll
            for (int m = 0; m < 4; ++m) {
                half8 kf = *(half8*)&Kl[w][16 * m + l15][kt * 32 + g * 8];
#pragma unroll
                for (int qj = 0; qj < 4; ++qj)
                    St[m][qj] = MFMA16(kf, qf[qj][kt], St[m][qj]);
            }
        // online softmax over kv (per-lane partial, then across g via shfl 16/32)
#pragma unroll
        for (int qj = 0; qj < 4; ++qj) {
            float tm = -1e30f;
#pragma unroll
            for (int m = 0; m < 4; ++m)
#pragma unroll
                for (int r = 0; r < 4; ++r) tm = fmaxf(tm, St[m][qj][r]);
            tm = fmaxf(tm, __shfl_xor(tm, 16));
            tm = fmaxf(tm, __shfl_xor(tm, 32));
            const float mn = fmaxf(ms[qj], tm);
            const float alpha = __expf(ms[qj] - mn);
            ms[qj] = mn;
            float ps = 0.f;
#pragma unroll
            for (int m = 0; m < 4; ++m)
#pragma unroll
                for (int r = 0; r < 4; ++r) {
                    const float p = __expf(St[m][qj][r] - mn);
                    St[m][qj][r] = p; ps += p;
                }
            ps += __shfl_xor(ps, 16);
            ps += __shfl_xor(ps, 32);
            ls[qj] = ls[qj] * alpha + ps;
#pragma unroll
            for (int di = 0; di < 4; ++di) {
                O[di][qj][0] *= alpha; O[di][qj][1] *= alpha;
                O[di][qj][2] *= alpha; O[di][qj][3] *= alpha;
            }
        }
        // P fragments direct from St registers (k-map: {4g+j, 16+4g+(j-4)})
        half8 pf[4][2];
#pragma unroll
        for (int qj = 0; qj < 4; ++qj)
#pragma unroll
            for (int kt = 0; kt < 2; ++kt) {
                half8 p;
                p[0] = (_Float16)St[2 * kt][qj][0]; p[1] = (_Float16)St[2 * kt][qj][1];
                p[2] = (_Float16)St[2 * kt][qj][2]; p[3] = (_Float16)St[2 * kt][qj][3];
                p[4] = (_Float16)St[2 * kt + 1][qj][0]; p[5] = (_Float16)St[2 * kt + 1][qj][1];
                p[6] = (_Float16)St[2 * kt + 1][qj][2]; p[7] = (_Float16)St[2 * kt + 1][qj][3];
                pf[qj][kt] = p;
            }
        // O^T[d][q] += V^T · P^T  (V frags use the same split k-map)
#pragma unroll
        for (int kt = 0; kt < 2; ++kt)
#pragma unroll
            for (int di = 0; di < 4; ++di) {
                half4 lo = *(half4*)&Vl[w][16 * di + l15][kt * 32 + 4 * g];
                half4 hi = *(half4*)&Vl[w][16 * di + l15][kt * 32 + 16 + 4 * g];
                half8 vf;
                vf[0] = lo[0]; vf[1] = lo[1]; vf[2] = lo[2]; vf[3] = lo[3];
                vf[4] = hi[0]; vf[5] = hi[1]; vf[6] = hi[2]; vf[7] = hi[3];
#pragma unroll
                for (int qj = 0; qj < 4; ++qj)
                    O[di][qj] = MFMA16(vf, pf[qj][kt], O[di][qj]);
            }
    }
    // epilogue: O^T/l -> AO[(s*4+b)*512 + h*64 + d] f16
#pragma unroll
    for (int qj = 0; qj < 4; ++qj) {
        const float inv = 1.0f / ls[qj];
        const int q = s0 + 16 * qj + l15;
        _Float16* dst = AO + ((size_t)q * 4 + b) * 512 + h * 64;
#pragma unroll
        for (int di = 0; di < 4; ++di) {
            half4 o;
            o[0] = (_Float16)(O[di][qj][0] * inv); o[1] = (_Float16)(O[di][qj][1] * inv);
            o[2] = (_Float16)(O[di][qj][2] * inv); o[3] = (_Float16)(O[di][qj][3] * inv);
            *(half4*)(dst + 16 * di + 4 * g) = o;
        }
    }
}

// ---------------- K3: output projection (f16 MFMA, f32 out) ----------------
__global__ __launch_bounds__(256) void oproj_mfma(
    const _Float16* __restrict__ A, const float* __restrict__ W,
    const float* __restrict__ bias, float* __restrict__ Out)
{
    __shared__ _Float16 As[128][72];
    __shared__ _Float16 Bs[64][72];
    const int tid = threadIdx.x;
    const int lane = tid & 63, wv = tid >> 6;
    const int l15 = lane & 15, g = lane >> 4;
    const int wr = wv >> 1, wc = wv & 1;
    const int j0 = blockIdx.x * 64, r0 = blockIdx.y * 128;
    f32x4 acc[4][2] = {};
    const int arow = tid >> 1, ahf = tid & 1;
    const int brow = tid >> 2, bc = tid & 3;
    for (int k0 = 0; k0 < 512; k0 += 64) {
        const _Float16* srca = A + (size_t)(r0 + arow) * 512 + k0 + ahf * 32;
#pragma unroll
        for (int c = 0; c < 4; ++c)
            *(half8*)&As[arow][ahf * 32 + c * 8] = *(const half8*)(srca + c * 8);
        const float* srcb = W + (size_t)(j0 + brow) * 512 + k0 + bc * 16;
#pragma unroll
        for (int c = 0; c < 2; ++c)
            *(half8*)&Bs[brow][bc * 16 + c * 8] = cvt8(srcb + c * 8);
        __syncthreads();
#pragma unroll
        for (int kt = 0; kt < 2; ++kt) {
            half8 bf0 = *(half8*)&Bs[32 * wc + l15][kt * 32 + g * 8];
            half8 bf1 = *(half8*)&Bs[32 * wc + 16 + l15][kt * 32 + g * 8];
#pragma unroll
            for (int ri = 0; ri < 4; ++ri) {
                half8 af = *(half8*)&As[64 * wr + 16 * ri + l15][kt * 32 + g * 8];
                acc[ri][0] = MFMA16(af, bf0, acc[ri][0]);
                acc[ri][1] = MFMA16(af, bf1, acc[ri][1]);
            }
        }
        __syncthreads();
    }
#pragma unroll
    for (int ri = 0; ri < 4; ++ri) {
#pragma unroll
        for (int cj = 0; cj < 2; ++cj) {
            const int col = j0 + 32 * wc + 16 * cj + l15;
            const float bv = bias[col];
#pragma unroll
            for (int r = 0; r < 4; ++r) {
                const int row = r0 + 64 * wr + 16 * ri + 4 * g + r;
                Out[(size_t)row * 512 + col] = acc[ri][cj][r] + bv;
            }
        }
    }
}

extern "C" void kernel_launch(void* const* d_in, const int* in_sizes, int n_in,
                              void* d_out, int out_size, void* d_ws, size_t ws_size,
                              hipStream_t stream)
{
    (void)in_sizes; (void)n_in; (void)out_size; (void)ws_size;
    const float* X    = (const float*)d_in[0];  // (S,B,D)
    const float* Mask = (const float*)d_in[1];  // (H,S,S)
    const float* gate = (const float*)d_in[2];  // (1,B,1)
    const float* Wi   = (const float*)d_in[3];  // (3D,D)
    const float* bi   = (const float*)d_in[4];  // (3D)
    const float* Wo   = (const float*)d_in[5];  // (D,D)
    const float* bo   = (const float*)d_in[6];  // (D)
    _Float16* ws = (_Float16*)d_ws;
    const size_t plane = (size_t)4 * 8 * 2048 * 64;  // 4.19M f16
    _Float16* Qh = ws;
    _Float16* Kh = ws + plane;
    _Float16* Vt = ws + 2 * plane;
    _Float16* AO = ws + 3 * plane;

    qkv_mfma<<<dim3(24, 64), 256, 0, stream>>>(X, Wi, bi, gate, Qh, Kh, Vt);
    attn_mfma<<<dim3(512), 128, 0, stream>>>(Qh, Kh, Vt, Mask, AO);
    oproj_mfma<<<dim3(8, 64), 256, 0, stream>>>(AO, Wo, bo, (float*)d_out);
}

// Round 3
// 178.351 us; speedup vs baseline: 5.0598x; 1.2973x over previous
//
#include <hip/hip_runtime.h>
#include <cstdint>
#include <cstddef>

typedef _Float16 half8 __attribute__((ext_vector_type(8)));
typedef _Float16 half4 __attribute__((ext_vector_type(4)));
typedef float f32x4 __attribute__((ext_vector_type(4)));

#define MFMA16(A,B,C) __builtin_amdgcn_mfma_f32_16x16x32_f16(A,B,C,0,0,0)

// convert 8 consecutive f32 -> half8
__device__ __forceinline__ half8 cvt8(const float* p) {
    f32x4 v0 = *(const f32x4*)p;
    f32x4 v1 = *(const f32x4*)(p + 4);
    half8 r;
    r[0]=(_Float16)v0[0]; r[1]=(_Float16)v0[1]; r[2]=(_Float16)v0[2]; r[3]=(_Float16)v0[3];
    r[4]=(_Float16)v1[0]; r[5]=(_Float16)v1[1]; r[6]=(_Float16)v1[2]; r[7]=(_Float16)v1[3];
    return r;
}

// ---------------- K1: QKV projection (f16 MFMA) ----------------
__global__ __launch_bounds__(256) void qkv_mfma(
    const float* __restrict__ X, const float* __restrict__ W,
    const float* __restrict__ bias, const float* __restrict__ gate,
    _Float16* __restrict__ Qo, _Float16* __restrict__ Ko, _Float16* __restrict__ Vt)
{
    __shared__ _Float16 As[128][72];
    __shared__ _Float16 Bs[64][72];
    const int tid = threadIdx.x;
    const int lane = tid & 63, wv = tid >> 6;
    const int l15 = lane & 15, g = lane >> 4;
    const int wr = wv >> 1, wc = wv & 1;
    const int j0 = blockIdx.x * 64, r0 = blockIdx.y * 128;
    f32x4 acc[4][2] = {};
    const int arow = tid >> 1, ahf = tid & 1;
    const int brow = tid >> 2, bc = tid & 3;
    for (int k0 = 0; k0 < 512; k0 += 64) {
        const float* srca = X + (size_t)(r0 + arow) * 512 + k0 + ahf * 32;
#pragma unroll
        for (int c = 0; c < 4; ++c)
            *(half8*)&As[arow][ahf * 32 + c * 8] = cvt8(srca + c * 8);
        const float* srcb = W + (size_t)(j0 + brow) * 512 + k0 + bc * 16;
#pragma unroll
        for (int c = 0; c < 2; ++c)
            *(half8*)&Bs[brow][bc * 16 + c * 8] = cvt8(srcb + c * 8);
        __syncthreads();
#pragma unroll
        for (int kt = 0; kt < 2; ++kt) {
            half8 bf0 = *(half8*)&Bs[32 * wc + l15][kt * 32 + g * 8];
            half8 bf1 = *(half8*)&Bs[32 * wc + 16 + l15][kt * 32 + g * 8];
#pragma unroll
            for (int ri = 0; ri < 4; ++ri) {
                half8 af = *(half8*)&As[64 * wr + 16 * ri + l15][kt * 32 + g * 8];
                acc[ri][0] = MFMA16(af, bf0, acc[ri][0]);
                acc[ri][1] = MFMA16(af, bf1, acc[ri][1]);
            }
        }
        __syncthreads();
    }
#pragma unroll
    for (int ri = 0; ri < 4; ++ri) {
#pragma unroll
        for (int cj = 0; cj < 2; ++cj) {
            const int col = j0 + 32 * wc + 16 * cj + l15;
            const int sec = col >> 9, hh = (col >> 6) & 7, d = col & 63;
            const float bv = bias[col];
#pragma unroll
            for (int r = 0; r < 4; ++r) {
                const int row = r0 + 64 * wr + 16 * ri + 4 * g + r;
                const int b = row & 3, s = row >> 2;
                const float v = acc[ri][cj][r];
                if (sec == 0)
                    Qo[((size_t)(b * 8 + hh) * 2048 + s) * 64 + d] = (_Float16)((v + bv) * 0.125f);
                else if (sec == 1)
                    Ko[((size_t)(b * 8 + hh) * 2048 + s) * 64 + d] = (_Float16)(v + bv);
                else
                    Vt[((size_t)(b * 8 + hh) * 64 + d) * 2048 + s] = (_Float16)(v * gate[b] + bv);
            }
        }
    }
}

// ---------------- K2: flash attention, 4 waves/block share (b,h)+K/V stage ----------------
// Wave w handles 32 q-rows (s0 = sg*128 + w*32). St[kv][q] = K·Q^T with mask as
// C-init (register-prefetched 1 tile ahead). K/V staged via regs (async split).
__global__ __launch_bounds__(256) void attn_mfma(
    const _Float16* __restrict__ Q, const _Float16* __restrict__ K,
    const _Float16* __restrict__ V, const float* __restrict__ M,
    _Float16* __restrict__ AO)
{
    __shared__ _Float16 Kl[64][72];
    __shared__ _Float16 Vl[64][72];
    const int tid = threadIdx.x;
    const int lane = tid & 63, w = tid >> 6;
    const int l15 = lane & 15, g = lane >> 4;
    const int bid = blockIdx.x;
    const int h = bid & 7, b = (bid >> 3) & 3, sg = bid >> 5;
    const int s0 = sg * 128 + w * 32;
    const size_t bh = (size_t)b * 8 + h;
    const _Float16* Qp = Q + bh * 2048 * 64;
    const _Float16* Kp = K + bh * 2048 * 64;
    const _Float16* Vp = V + bh * 64 * 2048;
    const float* Mp = M + (size_t)h * 2048 * 2048;

    // Q fragments direct from global
    half8 qf[2][2];
#pragma unroll
    for (int qj = 0; qj < 2; ++qj)
#pragma unroll
        for (int kt = 0; kt < 2; ++kt)
            qf[qj][kt] = *(const half8*)(Qp + (size_t)(s0 + 16 * qj + l15) * 64 + kt * 32 + g * 8);

    // stage-reg prologue (tile 0): thread covers K row srow cols [scg,scg+16) and same for V^T
    const int srow = tid >> 2, scg = (tid & 3) * 16;
    half8 kr0 = *(const half8*)(Kp + (size_t)srow * 64 + scg);
    half8 kr1 = *(const half8*)(Kp + (size_t)srow * 64 + scg + 8);
    half8 vr0 = *(const half8*)(Vp + (size_t)srow * 2048 + scg);
    half8 vr1 = *(const half8*)(Vp + (size_t)srow * 2048 + scg + 8);

    // mask prefetch (tile 0)
    f32x4 mc[4][2];
#pragma unroll
    for (int m = 0; m < 4; ++m)
#pragma unroll
        for (int qj = 0; qj < 2; ++qj)
            mc[m][qj] = *(const f32x4*)(Mp + (size_t)(s0 + 16 * qj + l15) * 2048 + 16 * m + 4 * g);

    f32x4 O[4][2] = {};
    float ms[2] = {-1e30f, -1e30f}, ls[2] = {0.f, 0.f};

    for (int t0 = 0; t0 < 2048; t0 += 64) {
        __syncthreads();   // prev-iter readers of Kl/Vl done
        *(half8*)&Kl[srow][scg]     = kr0;
        *(half8*)&Kl[srow][scg + 8] = kr1;
        *(half8*)&Vl[srow][scg]     = vr0;
        *(half8*)&Vl[srow][scg + 8] = vr1;
        __syncthreads();

        // QK^T with mask as C-init
        f32x4 St[4][2];
#pragma unroll
        for (int m = 0; m < 4; ++m) {
            half8 kf0 = *(half8*)&Kl[16 * m + l15][g * 8];
            half8 kf1 = *(half8*)&Kl[16 * m + l15][32 + g * 8];
#pragma unroll
            for (int qj = 0; qj < 2; ++qj) {
                St[m][qj] = MFMA16(kf0, qf[qj][0], mc[m][qj]);
                St[m][qj] = MFMA16(kf1, qf[qj][1], St[m][qj]);
            }
        }

        // prefetch next tile (K/V stage regs + mask) — hidden under softmax+PV
        const int tn = (t0 + 64 < 2048) ? t0 + 64 : 0;
        kr0 = *(const half8*)(Kp + (size_t)(tn + srow) * 64 + scg);
        kr1 = *(const half8*)(Kp + (size_t)(tn + srow) * 64 + scg + 8);
        vr0 = *(const half8*)(Vp + (size_t)srow * 2048 + tn + scg);
        vr1 = *(const half8*)(Vp + (size_t)srow * 2048 + tn + scg + 8);
#pragma unroll
        for (int m = 0; m < 4; ++m)
#pragma unroll
            for (int qj = 0; qj < 2; ++qj)
                mc[m][qj] = *(const f32x4*)(Mp + (size_t)(s0 + 16 * qj + l15) * 2048 + tn + 16 * m + 4 * g);

        // online softmax over kv with defer-max (THR=8)
#pragma unroll
        for (int qj = 0; qj < 2; ++qj) {
            float tm = -1e30f;
#pragma unroll
            for (int m = 0; m < 4; ++m)
#pragma unroll
                for (int r = 0; r < 4; ++r) tm = fmaxf(tm, St[m][qj][r]);
            tm = fmaxf(tm, __shfl_xor(tm, 16));
            tm = fmaxf(tm, __shfl_xor(tm, 32));
            if (!__all(tm <= ms[qj] + 8.0f)) {
                const float mn = fmaxf(ms[qj], tm);
                const float al = __expf(ms[qj] - mn);
                ls[qj] *= al;
#pragma unroll
                for (int di = 0; di < 4; ++di) {
                    O[di][qj][0] *= al; O[di][qj][1] *= al;
                    O[di][qj][2] *= al; O[di][qj][3] *= al;
                }
                ms[qj] = mn;
            }
            float ps = 0.f;
#pragma unroll
            for (int m = 0; m < 4; ++m)
#pragma unroll
                for (int r = 0; r < 4; ++r) {
                    const float p = __expf(St[m][qj][r] - ms[qj]);
                    St[m][qj][r] = p; ps += p;
                }
            ps += __shfl_xor(ps, 16);
            ps += __shfl_xor(ps, 32);
            ls[qj] += ps;
        }

        // P fragments direct from St registers (k-map {4g+j, 16+4g+(j-4)})
        half8 pf[2][2];
#pragma unroll
        for (int qj = 0; qj < 2; ++qj)
#pragma unroll
            for (int kt = 0; kt < 2; ++kt) {
                half8 p;
                p[0] = (_Float16)St[2 * kt][qj][0]; p[1] = (_Float16)St[2 * kt][qj][1];
                p[2] = (_Float16)St[2 * kt][qj][2]; p[3] = (_Float16)St[2 * kt][qj][3];
                p[4] = (_Float16)St[2 * kt + 1][qj][0]; p[5] = (_Float16)St[2 * kt + 1][qj][1];
                p[6] = (_Float16)St[2 * kt + 1][qj][2]; p[7] = (_Float16)St[2 * kt + 1][qj][3];
                pf[qj][kt] = p;
            }

        // O^T[d][q] += V^T · P^T (V frags use the same split k-map)
#pragma unroll
        for (int kt = 0; kt < 2; ++kt)
#pragma unroll
            for (int di = 0; di < 4; ++di) {
                half4 lo = *(half4*)&Vl[16 * di + l15][kt * 32 + 4 * g];
                half4 hi = *(half4*)&Vl[16 * di + l15][kt * 32 + 16 + 4 * g];
                half8 vf;
                vf[0] = lo[0]; vf[1] = lo[1]; vf[2] = lo[2]; vf[3] = lo[3];
                vf[4] = hi[0]; vf[5] = hi[1]; vf[6] = hi[2]; vf[7] = hi[3];
#pragma unroll
                for (int qj = 0; qj < 2; ++qj)
                    O[di][qj] = MFMA16(vf, pf[qj][kt], O[di][qj]);
            }
    }

    // epilogue: O^T/l -> AO[(s*4+b)*512 + h*64 + d] f16
#pragma unroll
    for (int qj = 0; qj < 2; ++qj) {
        const float inv = 1.0f / ls[qj];
        const int q = s0 + 16 * qj + l15;
        _Float16* dst = AO + ((size_t)q * 4 + b) * 512 + h * 64;
#pragma unroll
        for (int di = 0; di < 4; ++di) {
            half4 o;
            o[0] = (_Float16)(O[di][qj][0] * inv); o[1] = (_Float16)(O[di][qj][1] * inv);
            o[2] = (_Float16)(O[di][qj][2] * inv); o[3] = (_Float16)(O[di][qj][3] * inv);
            *(half4*)(dst + 16 * di + 4 * g) = o;
        }
    }
}

// ---------------- K3: output projection (f16 MFMA, f32 out) ----------------
__global__ __launch_bounds__(256) void oproj_mfma(
    const _Float16* __restrict__ A, const float* __restrict__ W,
    const float* __restrict__ bias, float* __restrict__ Out)
{
    __shared__ _Float16 As[128][72];
    __shared__ _Float16 Bs[64][72];
    const int tid = threadIdx.x;
    const int lane = tid & 63, wv = tid >> 6;
    const int l15 = lane & 15, g = lane >> 4;
    const int wr = wv >> 1, wc = wv & 1;
    const int j0 = blockIdx.x * 64, r0 = blockIdx.y * 128;
    f32x4 acc[4][2] = {};
    const int arow = tid >> 1, ahf = tid & 1;
    const int brow = tid >> 2, bc = tid & 3;
    for (int k0 = 0; k0 < 512; k0 += 64) {
        const _Float16* srca = A + (size_t)(r0 + arow) * 512 + k0 + ahf * 32;
#pragma unroll
        for (int c = 0; c < 4; ++c)
            *(half8*)&As[arow][ahf * 32 + c * 8] = *(const half8*)(srca + c * 8);
        const float* srcb = W + (size_t)(j0 + brow) * 512 + k0 + bc * 16;
#pragma unroll
        for (int c = 0; c < 2; ++c)
            *(half8*)&Bs[brow][bc * 16 + c * 8] = cvt8(srcb + c * 8);
        __syncthreads();
#pragma unroll
        for (int kt = 0; kt < 2; ++kt) {
            half8 bf0 = *(half8*)&Bs[32 * wc + l15][kt * 32 + g * 8];
            half8 bf1 = *(half8*)&Bs[32 * wc + 16 + l15][kt * 32 + g * 8];
#pragma unroll
            for (int ri = 0; ri < 4; ++ri) {
                half8 af = *(half8*)&As[64 * wr + 16 * ri + l15][kt * 32 + g * 8];
                acc[ri][0] = MFMA16(af, bf0, acc[ri][0]);
                acc[ri][1] = MFMA16(af, bf1, acc[ri][1]);
            }
        }
        __syncthreads();
    }
#pragma unroll
    for (int ri = 0; ri < 4; ++ri) {
#pragma unroll
        for (int cj = 0; cj < 2; ++cj) {
            const int col = j0 + 32 * wc + 16 * cj + l15;
            const float bv = bias[col];
#pragma unroll
            for (int r = 0; r < 4; ++r) {
                const int row = r0 + 64 * wr + 16 * ri + 4 * g + r;
                Out[(size_t)row * 512 + col] = acc[ri][cj][r] + bv;
            }
        }
    }
}

extern "C" void kernel_launch(void* const* d_in, const int* in_sizes, int n_in,
                              void* d_out, int out_size, void* d_ws, size_t ws_size,
                              hipStream_t stream)
{
    (void)in_sizes; (void)n_in; (void)out_size; (void)ws_size;
    const float* X    = (const float*)d_in[0];  // (S,B,D)
    const float* Mask = (const float*)d_in[1];  // (H,S,S)
    const float* gate = (const float*)d_in[2];  // (1,B,1)
    const float* Wi   = (const float*)d_in[3];  // (3D,D)
    const float* bi   = (const float*)d_in[4];  // (3D)
    const float* Wo   = (const float*)d_in[5];  // (D,D)
    const float* bo   = (const float*)d_in[6];  // (D)
    _Float16* ws = (_Float16*)d_ws;
    const size_t plane = (size_t)4 * 8 * 2048 * 64;  // 4.19M f16
    _Float16* Qh = ws;
    _Float16* Kh = ws + plane;
    _Float16* Vt = ws + 2 * plane;
    _Float16* AO = ws + 3 * plane;

    qkv_mfma<<<dim3(24, 64), 256, 0, stream>>>(X, Wi, bi, gate, Qh, Kh, Vt);
    attn_mfma<<<dim3(512), 256, 0, stream>>>(Qh, Kh, Vt, Mask, AO);
    oproj_mfma<<<dim3(8, 64), 256, 0, stream>>>(AO, Wo, bo, (float*)d_out);
}

// Round 4
// 142.868 us; speedup vs baseline: 6.3165x; 1.2484x over previous
//
#include <hip/hip_runtime.h>
#include <cstdint>
#include <cstddef>

typedef _Float16 half8 __attribute__((ext_vector_type(8)));
typedef _Float16 half4 __attribute__((ext_vector_type(4)));
typedef float f32x4 __attribute__((ext_vector_type(4)));

#define MFMA16(A,B,C) __builtin_amdgcn_mfma_f32_16x16x32_f16(A,B,C,0,0,0)

// ---------------- K0: bulk f32 -> f16 convert (X, Wi, Wo) ----------------
__global__ __launch_bounds__(256) void cvt_f16(
    const float* __restrict__ X, const float* __restrict__ Wi, const float* __restrict__ Wo,
    _Float16* __restrict__ Xh, _Float16* __restrict__ Wih, _Float16* __restrict__ Woh)
{
    const size_t i8 = ((size_t)blockIdx.x * 256 + threadIdx.x) * 8;
    const size_t NX = (size_t)4194304, NWI = 786432;
    const float* src; _Float16* dst; size_t off;
    if (i8 < NX) { src = X; dst = Xh; off = i8; }
    else if (i8 < NX + NWI) { src = Wi; dst = Wih; off = i8 - NX; }
    else { src = Wo; dst = Woh; off = i8 - NX - NWI; }
    f32x4 v0 = *(const f32x4*)(src + off);
    f32x4 v1 = *(const f32x4*)(src + off + 4);
    half8 r;
    r[0]=(_Float16)v0[0]; r[1]=(_Float16)v0[1]; r[2]=(_Float16)v0[2]; r[3]=(_Float16)v0[3];
    r[4]=(_Float16)v1[0]; r[5]=(_Float16)v1[1]; r[6]=(_Float16)v1[2]; r[7]=(_Float16)v1[3];
    *(half8*)(dst + off) = r;
}

// ---------------- K1: QKV projection (f16 MFMA, f16 inputs) ----------------
__global__ __launch_bounds__(256) void qkv_mfma(
    const _Float16* __restrict__ X, const _Float16* __restrict__ W,
    const float* __restrict__ bias, const float* __restrict__ gate,
    _Float16* __restrict__ Qo, _Float16* __restrict__ Ko, _Float16* __restrict__ Vt)
{
    __shared__ _Float16 As[128][72];
    __shared__ _Float16 Bs[64][72];
    const int tid = threadIdx.x;
    const int lane = tid & 63, wv = tid >> 6;
    const int l15 = lane & 15, g = lane >> 4;
    const int wr = wv >> 1, wc = wv & 1;
    const int j0 = blockIdx.x * 64, r0 = blockIdx.y * 128;
    f32x4 acc[4][2] = {};
    const int arow = tid >> 1, ahf = tid & 1;
    const int brow = tid >> 2, bc = tid & 3;
    for (int k0 = 0; k0 < 512; k0 += 64) {
        const _Float16* srca = X + (size_t)(r0 + arow) * 512 + k0 + ahf * 32;
#pragma unroll
        for (int c = 0; c < 4; ++c)
            *(half8*)&As[arow][ahf * 32 + c * 8] = *(const half8*)(srca + c * 8);
        const _Float16* srcb = W + (size_t)(j0 + brow) * 512 + k0 + bc * 16;
#pragma unroll
        for (int c = 0; c < 2; ++c)
            *(half8*)&Bs[brow][bc * 16 + c * 8] = *(const half8*)(srcb + c * 8);
        __syncthreads();
#pragma unroll
        for (int kt = 0; kt < 2; ++kt) {
            half8 bf0 = *(half8*)&Bs[32 * wc + l15][kt * 32 + g * 8];
            half8 bf1 = *(half8*)&Bs[32 * wc + 16 + l15][kt * 32 + g * 8];
#pragma unroll
            for (int ri = 0; ri < 4; ++ri) {
                half8 af = *(half8*)&As[64 * wr + 16 * ri + l15][kt * 32 + g * 8];
                acc[ri][0] = MFMA16(af, bf0, acc[ri][0]);
                acc[ri][1] = MFMA16(af, bf1, acc[ri][1]);
            }
        }
        __syncthreads();
    }
#pragma unroll
    for (int ri = 0; ri < 4; ++ri) {
#pragma unroll
        for (int cj = 0; cj < 2; ++cj) {
            const int col = j0 + 32 * wc + 16 * cj + l15;
            const int sec = col >> 9, hh = (col >> 6) & 7, d = col & 63;
            const float bv = bias[col];
#pragma unroll
            for (int r = 0; r < 4; ++r) {
                const int row = r0 + 64 * wr + 16 * ri + 4 * g + r;
                const int b = row & 3, s = row >> 2;
                const float v = acc[ri][cj][r];
                if (sec == 0)
                    Qo[((size_t)(b * 8 + hh) * 2048 + s) * 64 + d] = (_Float16)((v + bv) * 0.125f);
                else if (sec == 1)
                    Ko[((size_t)(b * 8 + hh) * 2048 + s) * 64 + d] = (_Float16)(v + bv);
                else
                    Vt[((size_t)(b * 8 + hh) * 64 + d) * 2048 + s] = (_Float16)(v * gate[b] + bv);
            }
        }
    }
}

// ---------------- K2: flash attention, 16 q-rows/wave, 1-barrier/tile dbuf ----------------
__global__ __launch_bounds__(256, 4) void attn_mfma(
    const _Float16* __restrict__ Q, const _Float16* __restrict__ K,
    const _Float16* __restrict__ V, const float* __restrict__ M,
    _Float16* __restrict__ AO)
{
    __shared__ _Float16 Kl[2][64][72];
    __shared__ _Float16 Vl[2][64][76];
    const int tid = threadIdx.x;
    const int lane = tid & 63, w = tid >> 6;
    const int l15 = lane & 15, g = lane >> 4;
    const int bid = blockIdx.x;
    const int h = bid & 7, b = (bid >> 3) & 3, sg = bid >> 5;
    const int s0 = sg * 64 + w * 16;
    const size_t bh = (size_t)b * 8 + h;
    const _Float16* Qp = Q + bh * 2048 * 64;
    const _Float16* Kp = K + bh * 2048 * 64;
    const _Float16* Vp = V + bh * 64 * 2048;
    const float* Mp = M + (size_t)h * 2048 * 2048;

    // Q fragments direct from global (16 rows)
    half8 qf[2];
#pragma unroll
    for (int kt = 0; kt < 2; ++kt)
        qf[kt] = *(const half8*)(Qp + (size_t)(s0 + l15) * 64 + kt * 32 + g * 8);

    // stage-reg prologue (tile 0)
    const int srow = tid >> 2, scg = (tid & 3) * 16;
    half8 kr0 = *(const half8*)(Kp + (size_t)srow * 64 + scg);
    half8 kr1 = *(const half8*)(Kp + (size_t)srow * 64 + scg + 8);
    half8 vr0 = *(const half8*)(Vp + (size_t)srow * 2048 + scg);
    half8 vr1 = *(const half8*)(Vp + (size_t)srow * 2048 + scg + 8);

    // mask prefetch (tile 0)
    f32x4 mc[4];
#pragma unroll
    for (int m = 0; m < 4; ++m)
        mc[m] = *(const f32x4*)(Mp + (size_t)(s0 + l15) * 2048 + 16 * m + 4 * g);

    f32x4 O[4] = {};
    float ms = -1e30f, ls = 0.f;

    for (int t0 = 0; t0 < 2048; t0 += 64) {
        const int cur = (t0 >> 6) & 1;
        // write staged tile t0 into buf[cur] (readers of buf[cur] from t0-2 all
        // passed the t0-1 barrier; safe with one barrier per tile)
        *(half8*)&Kl[cur][srow][scg]     = kr0;
        *(half8*)&Kl[cur][srow][scg + 8] = kr1;
        *(half8*)&Vl[cur][srow][scg]     = vr0;
        *(half8*)&Vl[cur][srow][scg + 8] = vr1;
        // issue global loads for tile t0+64 (land during this tile's compute)
        const int tn = (t0 + 64 < 2048) ? t0 + 64 : 0;
        kr0 = *(const half8*)(Kp + (size_t)(tn + srow) * 64 + scg);
        kr1 = *(const half8*)(Kp + (size_t)(tn + srow) * 64 + scg + 8);
        vr0 = *(const half8*)(Vp + (size_t)srow * 2048 + tn + scg);
        vr1 = *(const half8*)(Vp + (size_t)srow * 2048 + tn + scg + 8);
        __syncthreads();

        // QK^T with mask as C-init
        f32x4 St[4];
#pragma unroll
        for (int m = 0; m < 4; ++m) {
            half8 kf0 = *(half8*)&Kl[cur][16 * m + l15][g * 8];
            half8 kf1 = *(half8*)&Kl[cur][16 * m + l15][32 + g * 8];
            St[m] = MFMA16(kf0, qf[0], mc[m]);
            St[m] = MFMA16(kf1, qf[1], St[m]);
        }
        // prefetch mask for next tile
#pragma unroll
        for (int m = 0; m < 4; ++m)
            mc[m] = *(const f32x4*)(Mp + (size_t)(s0 + l15) * 2048 + tn + 16 * m + 4 * g);

        // online softmax over kv (16 vals/lane + shfl over g), defer-max THR=8
        float tm = fmaxf(fmaxf(St[0][0], St[0][1]), St[0][2]);
        tm = fmaxf(fmaxf(tm, St[0][3]), fmaxf(St[1][0], St[1][1]));
        tm = fmaxf(fmaxf(tm, St[1][2]), fmaxf(St[1][3], St[2][0]));
        tm = fmaxf(fmaxf(tm, St[2][1]), fmaxf(St[2][2], St[2][3]));
        tm = fmaxf(fmaxf(tm, St[3][0]), fmaxf(St[3][1], St[3][2]));
        tm = fmaxf(tm, St[3][3]);
        tm = fmaxf(tm, __shfl_xor(tm, 16));
        tm = fmaxf(tm, __shfl_xor(tm, 32));
        if (!__all(tm <= ms + 8.0f)) {
            const float mn = fmaxf(ms, tm);
            const float al = __expf(ms - mn);
            ls *= al;
#pragma unroll
            for (int di = 0; di < 4; ++di) {
                O[di][0] *= al; O[di][1] *= al; O[di][2] *= al; O[di][3] *= al;
            }
            ms = mn;
        }
        float ps = 0.f;
#pragma unroll
        for (int m = 0; m < 4; ++m)
#pragma unroll
            for (int r = 0; r < 4; ++r) {
                const float p = __expf(St[m][r] - ms);
                St[m][r] = p; ps += p;
            }
        ps += __shfl_xor(ps, 16);
        ps += __shfl_xor(ps, 32);
        ls += ps;

        // P fragments from St regs (k-map {4g+j, 16+4g+(j-4)})
        half8 pf[2];
#pragma unroll
        for (int kt = 0; kt < 2; ++kt) {
            half8 p;
            p[0] = (_Float16)St[2 * kt][0]; p[1] = (_Float16)St[2 * kt][1];
            p[2] = (_Float16)St[2 * kt][2]; p[3] = (_Float16)St[2 * kt][3];
            p[4] = (_Float16)St[2 * kt + 1][0]; p[5] = (_Float16)St[2 * kt + 1][1];
            p[6] = (_Float16)St[2 * kt + 1][2]; p[7] = (_Float16)St[2 * kt + 1][3];
            pf[kt] = p;
        }

        // O^T[d][q] += V^T · P^T (V frags use the same split k-map)
#pragma unroll
        for (int kt = 0; kt < 2; ++kt)
#pragma unroll
            for (int di = 0; di < 4; ++di) {
                half4 lo = *(half4*)&Vl[cur][16 * di + l15][kt * 32 + 4 * g];
                half4 hi = *(half4*)&Vl[cur][16 * di + l15][kt * 32 + 16 + 4 * g];
                half8 vf;
                vf[0] = lo[0]; vf[1] = lo[1]; vf[2] = lo[2]; vf[3] = lo[3];
                vf[4] = hi[0]; vf[5] = hi[1]; vf[6] = hi[2]; vf[7] = hi[3];
                O[di] = MFMA16(vf, pf[kt], O[di]);
            }
    }

    // epilogue: O^T/l -> AO[(q*4+b)*512 + h*64 + d] f16
    const float inv = 1.0f / ls;
    const int q = s0 + l15;
    _Float16* dst = AO + ((size_t)q * 4 + b) * 512 + h * 64;
#pragma unroll
    for (int di = 0; di < 4; ++di) {
        half4 o;
        o[0] = (_Float16)(O[di][0] * inv); o[1] = (_Float16)(O[di][1] * inv);
        o[2] = (_Float16)(O[di][2] * inv); o[3] = (_Float16)(O[di][3] * inv);
        *(half4*)(dst + 16 * di + 4 * g) = o;
    }
}

// ---------------- K3: output projection (f16 inputs, f32 out) ----------------
__global__ __launch_bounds__(256) void oproj_mfma(
    const _Float16* __restrict__ A, const _Float16* __restrict__ W,
    const float* __restrict__ bias, float* __restrict__ Out)
{
    __shared__ _Float16 As[128][72];
    __shared__ _Float16 Bs[64][72];
    const int tid = threadIdx.x;
    const int lane = tid & 63, wv = tid >> 6;
    const int l15 = lane & 15, g = lane >> 4;
    const int wr = wv >> 1, wc = wv & 1;
    const int j0 = blockIdx.x * 64, r0 = blockIdx.y * 128;
    f32x4 acc[4][2] = {};
    const int arow = tid >> 1, ahf = tid & 1;
    const int brow = tid >> 2, bc = tid & 3;
    for (int k0 = 0; k0 < 512; k0 += 64) {
        const _Float16* srca = A + (size_t)(r0 + arow) * 512 + k0 + ahf * 32;
#pragma unroll
        for (int c = 0; c < 4; ++c)
            *(half8*)&As[arow][ahf * 32 + c * 8] = *(const half8*)(srca + c * 8);
        const _Float16* srcb = W + (size_t)(j0 + brow) * 512 + k0 + bc * 16;
#pragma unroll
        for (int c = 0; c < 2; ++c)
            *(half8*)&Bs[brow][bc * 16 + c * 8] = *(const half8*)(srcb + c * 8);
        __syncthreads();
#pragma unroll
        for (int kt = 0; kt < 2; ++kt) {
            half8 bf0 = *(half8*)&Bs[32 * wc + l15][kt * 32 + g * 8];
            half8 bf1 = *(half8*)&Bs[32 * wc + 16 + l15][kt * 32 + g * 8];
#pragma unroll
            for (int ri = 0; ri < 4; ++ri) {
                half8 af = *(half8*)&As[64 * wr + 16 * ri + l15][kt * 32 + g * 8];
                acc[ri][0] = MFMA16(af, bf0, acc[ri][0]);
                acc[ri][1] = MFMA16(af, bf1, acc[ri][1]);
            }
        }
        __syncthreads();
    }
#pragma unroll
    for (int ri = 0; ri < 4; ++ri) {
#pragma unroll
        for (int cj = 0; cj < 2; ++cj) {
            const int col = j0 + 32 * wc + 16 * cj + l15;
            const float bv = bias[col];
#pragma unroll
            for (int r = 0; r < 4; ++r) {
                const int row = r0 + 64 * wr + 16 * ri + 4 * g + r;
                Out[(size_t)row * 512 + col] = acc[ri][cj][r] + bv;
            }
        }
    }
}

extern "C" void kernel_launch(void* const* d_in, const int* in_sizes, int n_in,
                              void* d_out, int out_size, void* d_ws, size_t ws_size,
                              hipStream_t stream)
{
    (void)in_sizes; (void)n_in; (void)out_size; (void)ws_size;
    const float* X    = (const float*)d_in[0];  // (S,B,D)
    const float* Mask = (const float*)d_in[1];  // (H,S,S)
    const float* gate = (const float*)d_in[2];  // (1,B,1)
    const float* Wi   = (const float*)d_in[3];  // (3D,D)
    const float* bi   = (const float*)d_in[4];  // (3D)
    const float* Wo   = (const float*)d_in[5];  // (D,D)
    const float* bo   = (const float*)d_in[6];  // (D)
    _Float16* ws = (_Float16*)d_ws;
    const size_t plane = (size_t)4 * 8 * 2048 * 64;  // 4,194,304
    _Float16* Qh  = ws;
    _Float16* Kh  = ws + plane;
    _Float16* Vt  = ws + 2 * plane;
    _Float16* AO  = ws + 3 * plane;
    _Float16* Xh  = ws + 4 * plane;              // 4,194,304 (== plane)
    _Float16* Wih = ws + 5 * plane;              // 786,432
    _Float16* Woh = ws + 5 * plane + 786432;     // 262,144

    // total f32->f16 elements: 4194304 + 786432 + 262144 = 5242880 = 8*655360
    cvt_f16<<<dim3(2560), 256, 0, stream>>>(X, Wi, Wo, Xh, Wih, Woh);
    qkv_mfma<<<dim3(24, 64), 256, 0, stream>>>(Xh, Wih, bi, gate, Qh, Kh, Vt);
    attn_mfma<<<dim3(1024), 256, 0, stream>>>(Qh, Kh, Vt, Mask, AO);
    oproj_mfma<<<dim3(8, 64), 256, 0, stream>>>(AO, Woh, bo, (float*)d_out);
}